// Round 8
// baseline (866.839 us; speedup 1.0000x reference)
//
#include <hip/hip_runtime.h>
#include <cstdint>
#include <cstddef>

#define N_NEU 2048
#define B_SZ  256
#define D_IN  1024
#define T_STEPS 64

typedef _Float16 f16x8 __attribute__((ext_vector_type(8)));
typedef _Float16 f16x4 __attribute__((ext_vector_type(4)));
typedef float    f32x4 __attribute__((ext_vector_type(4)));
typedef unsigned u32x4 __attribute__((ext_vector_type(4)));

#define MFMA16(a, b, c) __builtin_amdgcn_mfma_f32_16x16x32_f16((a), (b), (c), 0, 0, 0)

// ---------------- ws layout (bytes) ----------------
// Wh      [2048][2048] f16   @ 0       (8 MB)
// Wl      [2048][2048] f16   @ 8 MB    (8 MB)
// Iext    [256][2048]  f32   @ 16 MB   (2 MB)
// bitmapv u64[2][256][64]    @ 18 MB   (256 KB)  epoch<<32 | 32 spike bits (word n/32 of row b)

// 8 bits -> 8 f16 (0.0 / 1.0)
__device__ inline f16x8 expand8(unsigned b) {
  u32x4 t;
  t[0] = ((b & 1u)   ? 0x3C00u : 0u) | ((b & 2u)   ? 0x3C000000u : 0u);
  t[1] = ((b & 4u)   ? 0x3C00u : 0u) | ((b & 8u)   ? 0x3C000000u : 0u);
  t[2] = ((b & 16u)  ? 0x3C00u : 0u) | ((b & 32u)  ? 0x3C000000u : 0u);
  t[3] = ((b & 64u)  ? 0x3C00u : 0u) | ((b & 128u) ? 0x3C000000u : 0u);
  return __builtin_bit_cast(f16x8, t);
}

// Split W_eff = adj*mask into f16 hi + f16 lo' (w ~= hi + lo'/4096, err ~2^-22).
// Also zero the epoch-tagged bitmap (replay determinism). float4-vectorized.
__global__ __launch_bounds__(256) void k_wsplit(const float* __restrict__ adj,
                                                const float* __restrict__ mask,
                                                _Float16* __restrict__ Wh,
                                                _Float16* __restrict__ Wl,
                                                unsigned long long* __restrict__ bitmapv) {
  const int idx = blockIdx.x * 256 + threadIdx.x;
  if (idx < 2 * 256 * 64) bitmapv[idx] = 0ull;
  const int total4 = (N_NEU * N_NEU) / 4;
  for (int i = idx; i < total4; i += gridDim.x * 256) {
    float4 a = ((const float4*)adj)[i];
    float4 m = ((const float4*)mask)[i];
    float w0 = a.x * m.x, w1 = a.y * m.y, w2 = a.z * m.z, w3 = a.w * m.w;
    f16x4 h, lo;
    h[0] = (_Float16)w0; lo[0] = (_Float16)((w0 - (float)h[0]) * 4096.0f);
    h[1] = (_Float16)w1; lo[1] = (_Float16)((w1 - (float)h[1]) * 4096.0f);
    h[2] = (_Float16)w2; lo[2] = (_Float16)((w2 - (float)h[2]) * 4096.0f);
    h[3] = (_Float16)w3; lo[3] = (_Float16)((w3 - (float)h[3]) * 4096.0f);
    ((f16x4*)Wh)[i] = h;
    ((f16x4*)Wl)[i] = lo;
  }
}

// I_ext = ext @ W_in^T + b_in, plain fp32. Proven absmax 0.0 (r1/r5/r6/r7).
__global__ __launch_bounds__(256) void k_iext(const float* __restrict__ ext,
                                              const float* __restrict__ Win,
                                              const float* __restrict__ bin,
                                              float* __restrict__ Iext) {
  __shared__ float At[32][68];
  __shared__ float Bt[32][68];
  const int tid = threadIdx.x;
  const int b0 = (blockIdx.x & 3) * 64;
  const int n0 = (blockIdx.x >> 2) * 64;
  const int tx = tid & 15, ty = tid >> 4;
  float acc[4][4] = {};
  for (int kt = 0; kt < D_IN / 32; ++kt) {
    const int k0 = kt * 32;
#pragma unroll
    for (int i = 0; i < 8; ++i) {
      int e = tid + i * 256;
      int kk = e & 31, row = e >> 5;
      At[kk][row] = ext[(size_t)(b0 + row) * D_IN + k0 + kk];
      Bt[kk][row] = Win[(size_t)(n0 + row) * D_IN + k0 + kk];
    }
    __syncthreads();
    for (int kk = 0; kk < 32; ++kk) {
      f32x4 a = *(const f32x4*)&At[kk][ty * 4];
      f32x4 b = *(const f32x4*)&Bt[kk][tx * 4];
#pragma unroll
      for (int i = 0; i < 4; ++i)
#pragma unroll
        for (int j = 0; j < 4; ++j) acc[i][j] += a[i] * b[j];
    }
    __syncthreads();
  }
#pragma unroll
  for (int i = 0; i < 4; ++i)
#pragma unroll
    for (int j = 0; j < 4; ++j)
      Iext[(size_t)(b0 + ty * 4 + i) * N_NEU + n0 + tx * 4 + j] = acc[i][j] + bin[n0 + tx * 4 + j];
}

// Split-K tree reduction over 8 waves via LDS. IDENTICAL to r5/r6/r7 (summation order preserved).
__device__ inline void reduce_tree(float (&outv)[4], const f32x4 (&c)[4][2],
                                   float* red, int tid) {
  const int lane = tid & 63, wv = tid >> 6;
  const int cb = lane & 15, rq = (lane >> 4) << 2;
  if (wv >= 4) {
    const int p = wv - 4;
#pragma unroll
    for (int mt = 0; mt < 4; ++mt)
#pragma unroll
      for (int nt = 0; nt < 2; ++nt) {
        const int col = nt * 16 + cb;
        const int r0 = (mt * 16 + rq) ^ ((col & 7) << 2);
        *(f32x4*)(red + (p * 32 + col) * 64 + r0) = c[mt][nt];
      }
  }
  __syncthreads();
  if (wv < 4) {
#pragma unroll
    for (int mt = 0; mt < 4; ++mt)
#pragma unroll
      for (int nt = 0; nt < 2; ++nt) {
        const int col = nt * 16 + cb;
        const int r0 = (mt * 16 + rq) ^ ((col & 7) << 2);
        float* p2 = red + (wv * 32 + col) * 64 + r0;
        f32x4 o = *(const f32x4*)p2;
        o += c[mt][nt];
        *(f32x4*)p2 = o;
      }
  }
  __syncthreads();
#pragma unroll
  for (int j = 0; j < 4; ++j) {
    const int o = j * 512 + tid;
    const int row = o >> 5, col = o & 31;
    const int rs = row ^ ((col & 7) << 2);
    float s = 0.0f;
#pragma unroll
    for (int p = 0; p < 4; ++p) s += red[(p * 32 + col) * 64 + rs];
    outv[j] = s;
  }
}

// Persistent fused LIF kernel, BARRIER-FREE dataflow.
// 256 blocks x 512 thr (1/CU, co-resident). Block (bg, ns): rows bg*64..+64, cols ns*32..+32.
// 8 waves split K. Wh+Wl resident in VGPRs. Spike words are self-flagging:
// u64 = (epoch<<32)|bits; consumers poll exactly the words they consume.
// 2-deep buffer rotation is race-free: a block reaching step t+1 has observed ALL
// epoch-t+1 stores, so nobody still reads the buffer it overwrites at epoch t+2.
__global__ __launch_bounds__(512, 2) void k_fused5(
    const _Float16* __restrict__ Wh, const _Float16* __restrict__ Wl,
    const float* __restrict__ Iext, unsigned long long* __restrict__ bmv,
    float* __restrict__ out) {
  __shared__ float red[4 * 32 * 64];      // 32 KB (reduce_tree, layout unchanged)
  __shared__ unsigned bm_lds[64 * 64];    // 16 KB: [row][word ^ ((row&7)<<2)]

  const int tid = threadIdx.x;
  const int lane = tid & 63;
  const int kw = tid >> 6;       // wave id = split-K index 0..7
  const int l15 = lane & 15;
  const int klo = lane >> 4;     // 0..3
  const int sh = klo * 8;
  const int bg = blockIdx.x >> 6;   // 0..3 batch group
  const int ns = blockIdx.x & 63;   // 0..63 neuron slice
  const int n0 = ns * 32;
  const float inv4096 = 1.0f / 4096.0f;
  const f32x4 z4 = {0.f, 0.f, 0.f, 0.f};

  // ---------- per-thread Iext (proven fp32 values from k_iext) ----------
  float Iext_r[4];
#pragma unroll
  for (int j = 0; j < 4; ++j)
    Iext_r[j] = Iext[(size_t)(bg * 64 + j * 16 + (tid >> 5)) * N_NEU + n0 + (tid & 31)];

  // ---------- resident Wh AND Wl fragments (K-loop is pure-register) ----------
  const _Float16* whb = Wh + (size_t)(n0 + l15) * N_NEU + kw * 256 + klo * 8;
  const _Float16* wlb = Wl + (size_t)(n0 + l15) * N_NEU + kw * 256 + klo * 8;
  f16x8 whf[2][8], wlf[2][8];
#pragma unroll
  for (int nt = 0; nt < 2; ++nt)
#pragma unroll
    for (int kcl = 0; kcl < 8; ++kcl) {
      whf[nt][kcl] = *(const f16x8*)(whb + nt * 16 * N_NEU + kcl * 32);
      wlf[nt][kcl] = *(const f16x8*)(wlb + nt * 16 * N_NEU + kcl * 32);
    }

  float V[4] = {0.f, 0.f, 0.f, 0.f};
  unsigned cnt[4] = {0u, 0u, 0u, 0u};

  for (int t = 0; t < T_STEPS; ++t) {
    float cI[4];
    if (t == 0) {
      cI[0] = cI[1] = cI[2] = cI[3] = 0.0f;
    } else {
      // ---- stage: poll epoch-tagged words (coalesced LLC u64 loads), bits -> LDS ----
      // thread's 8 words: g = i*512+tid -> row_local = i*8+kw, word = lane
      const unsigned long long* src =
          bmv + (size_t)(t & 1) * 16384 + (size_t)(bg * 64) * 64 + tid;
      const unsigned tgt = (unsigned)t;
      unsigned long long v[8];
      unsigned need = 0xFFu;
      while (need) {
#pragma unroll
        for (int i = 0; i < 8; ++i)
          if (need & (1u << i))
            v[i] = __hip_atomic_load(src + (size_t)i * 512,
                                     __ATOMIC_RELAXED, __HIP_MEMORY_SCOPE_AGENT);
#pragma unroll
        for (int i = 0; i < 8; ++i)
          if ((unsigned)(v[i] >> 32) == tgt) need &= ~(1u << i);
        if (need) __builtin_amdgcn_s_sleep(2);
      }
#pragma unroll
      for (int i = 0; i < 8; ++i) {
        const int row = i * 8 + kw;
        bm_lds[row * 64 + (lane ^ ((row & 7) << 2))] = (unsigned)v[i];
      }
      __syncthreads();

      // ---- K-loop: pure-register MFMA (identical math/order to r7) ----
      f32x4 acch[4][2], accl[4][2];
#pragma unroll
      for (int mt = 0; mt < 4; ++mt)
#pragma unroll
        for (int nt = 0; nt < 2; ++nt) { acch[mt][nt] = z4; accl[mt][nt] = z4; }

#pragma unroll
      for (int mt = 0; mt < 4; ++mt) {
        const int row = mt * 16 + l15;
        const int xm = (row & 7) << 2;
        const u32x4 qa = *(const u32x4*)&bm_lds[row * 64 + ((kw * 8) ^ xm)];
        const u32x4 qb = *(const u32x4*)&bm_lds[row * 64 + ((kw * 8 + 4) ^ xm)];
#pragma unroll
        for (int kcl = 0; kcl < 8; ++kcl) {
          const unsigned word = (kcl < 4) ? qa[kcl] : qb[kcl - 4];
          const f16x8 a = expand8((word >> sh) & 0xFFu);
          acch[mt][0] = MFMA16(a, whf[0][kcl], acch[mt][0]);
          accl[mt][0] = MFMA16(a, wlf[0][kcl], accl[mt][0]);
          acch[mt][1] = MFMA16(a, whf[1][kcl], acch[mt][1]);
          accl[mt][1] = MFMA16(a, wlf[1][kcl], accl[mt][1]);
        }
      }
      f32x4 cb[4][2];
#pragma unroll
      for (int mt = 0; mt < 4; ++mt)
#pragma unroll
        for (int nt = 0; nt < 2; ++nt) cb[mt][nt] = acch[mt][nt] + accl[mt][nt] * inv4096;
      reduce_tree(cI, cb, red, tid);
    }

    // ---------- fused LIF epilogue; self-flagging spike stores (epoch t+1) ----------
    const size_t wb = (size_t)((t + 1) & 1) * 16384;
    const unsigned long long ev = ((unsigned long long)(unsigned)(t + 1)) << 32;
#pragma unroll
    for (int j = 0; j < 4; ++j) {
      float I = cI[j] + Iext_r[j];
      float v = 0.9f * V[j] + I;
      bool sp = (v - 1.0f) >= 0.0f;
      V[j] = sp ? 0.0f : v;
      cnt[j] += sp ? 1u : 0u;
      if (t < T_STEPS - 1) {
        unsigned long long ba = __ballot(sp);
        const int row = bg * 64 + j * 16 + 2 * kw;   // lanes 0-31: row, lanes 32-63: row+1
        if (lane == 0)
          __hip_atomic_store(bmv + wb + (size_t)row * 64 + ns, ev | (unsigned)ba,
                             __ATOMIC_RELAXED, __HIP_MEMORY_SCOPE_AGENT);
        else if (lane == 32)
          __hip_atomic_store(bmv + wb + (size_t)(row + 1) * 64 + ns, ev | (unsigned)(ba >> 32),
                             __ATOMIC_RELAXED, __HIP_MEMORY_SCOPE_AGENT);
      }
    }
    // no barrier, no fence: next step's stage polls the epochs it needs
  }

  // ---------- write firing rates ----------
#pragma unroll
  for (int j = 0; j < 4; ++j) {
    const int row = j * 16 + (tid >> 5);
    out[(size_t)(bg * 64 + row) * N_NEU + n0 + (tid & 31)] = (float)cnt[j] * 0.015625f;
  }
}

extern "C" void kernel_launch(void* const* d_in, const int* in_sizes, int n_in,
                              void* d_out, int out_size, void* d_ws, size_t ws_size,
                              hipStream_t stream) {
  (void)in_sizes; (void)n_in; (void)out_size; (void)ws_size;
  const float* ext  = (const float*)d_in[0];
  const float* Win  = (const float*)d_in[1];
  const float* bin  = (const float*)d_in[2];
  const float* adj  = (const float*)d_in[3];
  const float* mask = (const float*)d_in[4];
  unsigned char* ws = (unsigned char*)d_ws;

  _Float16* Wh  = (_Float16*)(ws);
  _Float16* Wl  = (_Float16*)(ws + (size_t)(8u << 20));
  float*    Iext = (float*)  (ws + (size_t)(16u << 20));
  unsigned long long* bmv = (unsigned long long*)(ws + (size_t)(18u << 20));
  float* out = (float*)d_out;

  hipLaunchKernelGGL(k_wsplit, dim3(2048), dim3(256), 0, stream, adj, mask, Wh, Wl, bmv);
  hipLaunchKernelGGL(k_iext,   dim3(128),  dim3(256), 0, stream, ext, Win, bin, Iext);
  hipLaunchKernelGGL(k_fused5, dim3(256),  dim3(512), 0, stream,
                     Wh, Wl, Iext, bmv, out);
}